// Round 22
// baseline (31.136 us; speedup 1.0000x reference)
//
#include <hip/hip_runtime.h>

typedef _Float16 f16x4 __attribute__((ext_vector_type(4)));
typedef _Float16 f16x8 __attribute__((ext_vector_type(8)));
typedef __fp16 fp16x2 __attribute__((ext_vector_type(2)));   // cvt_pkrtz return type
typedef float f32x4 __attribute__((ext_vector_type(4)));
typedef float f32x2 __attribute__((ext_vector_type(2)));

#define SSTR 76              // row stride in halves (152B rows, 8B-aligned for b64; 23.0KB -> 7 blocks/CU)
#define NROWS 74             // staged rows (64 outputs + 10 halo)
#define NPT 6                // staging pair-tasks per thread (1480/256 = 5.8)

__device__ __forceinline__ f16x4 cvt4(f32x4 a)
{
    union { fp16x2 h2[2]; f16x4 f; } u;
    u.h2[0] = __builtin_amdgcn_cvt_pkrtz(a[0], a[1]);
    u.h2[1] = __builtin_amdgcn_cvt_pkrtz(a[2], a[3]);
    return u.f;
}

// ---- main: 64x64 output region per block (2 x 64x32 tiles), 4 waves, ONE barrier.
// H-pass: one mfma_f32_16x16x32_f16 per quantity; D-frag (row=4g+j) feeds vertical
// 16x16x16 B-frags directly in registers (validated R3/R5-R21).
// Quantities: mu1, mu2, A=conv((r+d)^2), B=conv((r-d)^2).
// XCD-bijective swizzle (R17). Paired-chunk staging (R19). Plain-store buckets (R20).
// LDS weight table (R21). R22: SSTR 88->76 (b64 LDS ops) => 7 blocks/CU;
// incremental task decode (no per-k magic-mul divides).
__global__ __launch_bounds__(256, 4) void ssim_main(
    const float* __restrict__ raw, const float* __restrict__ dst,
    const float* __restrict__ win, float* __restrict__ buckets)
{
    __shared__ __align__(16) _Float16 sr[NROWS * SSTR];
    __shared__ __align__(16) _Float16 sd[NROWS * SSTR];
    __shared__ __align__(16) _Float16 wrot[4][64];   // wrot[r][i] = w1[i+r-16] (0 outside)

    const int tid = threadIdx.x;
    const int wv = tid >> 6;           // wave = 16-wide x-strip
    const int lane = tid & 63;
    const int g = lane >> 4;
    const int ln = lane & 15;
    const int nt = wv;

    // XCD-bijective swizzle: 3072 blocks = 8 XCDs x 384-contiguous runs (R17)
    const int wg = blockIdx.x;
    const int sw = (wg & 7) * 384 + (wg >> 3);
    const int bz = sw >> 6;
    const int bx = sw & 7;
    const int by = (sw >> 3) & 7;

    const int gx0 = bx * 64;
    const int ybase32 = by * 64;                // first input row of the region
    const long ioff = (long)bz * (512 * 512);
    const float* rb = raw + ioff;
    const float* db = dst + ioff;

    // ---- staging: 1480 pair-tasks = 74 rows x {r,d} x 10 chunk-pairs (R19).
    // Incremental decode: pc += 6 (mod 10), sub += 25 (+carry) per k.
    float4 fvA[NPT], fvB[NPT];
    _Float16* dsts[NPT];
    const bool fastpath = (gx0 < 448) && (ybase32 < 448);
    {
        int pc = tid % 10;
        int sub = tid / 10;
        if (fastpath) {
#pragma unroll
            for (int k = 0; k < NPT; ++k) {
                if (k < NPT - 1 || tid < 200) {
                    int row = sub >> 1;
                    const float* src = ((sub & 1) ? db : rb) + (long)(ybase32 + row) * 512 + gx0 + 8 * pc;
                    fvA[k] = *reinterpret_cast<const float4*>(src);
                    fvB[k] = *reinterpret_cast<const float4*>(src + 4);
                    dsts[k] = ((sub & 1) ? sd : sr) + row * SSTR + pc * 8;
                } else {
                    dsts[k] = nullptr;
                }
                pc += 6; sub += 25;
                if (pc >= 10) { pc -= 10; sub += 1; }
            }
        } else {
#pragma unroll
            for (int k = 0; k < NPT; ++k) {
                if (k < NPT - 1 || tid < 200) {
                    int row = sub >> 1;
                    int gy = ybase32 + row; if (gy > 511) gy = 511;
                    int ca = gx0 + 8 * pc;     if (ca > 508) ca = 508;
                    int cb = ca + 4;           if (cb > 508) cb = 508;
                    const float* rowp = ((sub & 1) ? db : rb) + (long)gy * 512;
                    fvA[k] = *reinterpret_cast<const float4*>(rowp + ca);
                    fvB[k] = *reinterpret_cast<const float4*>(rowp + cb);
                    dsts[k] = ((sub & 1) ? sd : sr) + row * SSTR + pc * 8;
                } else {
                    dsts[k] = nullptr;
                }
                pc += 6; sub += 25;
                if (pc >= 10) { pc -= 10; sub += 1; }
            }
        }
    }

    // ---- rotated padded weight copies (pre-barrier; hides under staging loads) ----
    {
        int r = tid >> 6, i = tid & 63;
        int idx = i + r - 16;
        float val = 0.f;
        if (idx >= 0 && idx <= 10) {
#pragma unroll
            for (int j = 0; j < 11; ++j) val += win[idx * 11 + j];
        }
        wrot[r][i] = (_Float16)val;
    }

#pragma unroll
    for (int k = 0; k < NPT; ++k) {
        if (dsts[k]) {
            union { fp16x2 h2[2]; uint2 u; } pa, pb;
            pa.h2[0] = __builtin_amdgcn_cvt_pkrtz(fvA[k].x, fvA[k].y);
            pa.h2[1] = __builtin_amdgcn_cvt_pkrtz(fvA[k].z, fvA[k].w);
            pb.h2[0] = __builtin_amdgcn_cvt_pkrtz(fvB[k].x, fvB[k].y);
            pb.h2[1] = __builtin_amdgcn_cvt_pkrtz(fvB[k].z, fvB[k].w);
            *reinterpret_cast<uint2*>(dsts[k]) = pa.u;       // ds_write_b64
            *reinterpret_cast<uint2*>(dsts[k] + 4) = pb.u;   // ds_write_b64
        }
    }
    __syncthreads();

    // ---- weight fragments via aligned LDS reads (R21) ----
    f16x4 wf0, wf1;
    f16x8 wh;
    {
        int s = 4 * g - ln + 16;               // 1..28
        const char* b0 = (const char*)wrot[s & 3] + (s >> 2) * 8;
        wf0 = *(const f16x4*)(b0);
        wf1 = *(const f16x4*)(b0 + 32);        // +16 halves, same rotation
        int s2 = 8 * g - ln + 16;              // 1..40
        const char* b2 = (const char*)wrot[s2 & 3] + (s2 >> 2) * 8;
        union { f16x4 q[2]; f16x8 o; } uu;
        uu.q[0] = *(const f16x4*)(b2);
        uu.q[1] = *(const f16x4*)(b2 + 8);
        wh = uu.o;
    }

    float lsum = 0.f;
    const int ox = gx0 + 16 * nt + ln;

#pragma unroll
    for (int it = 0; it < 2; ++it) {
        // ---- horizontal conv: ONE 16x16x32 MFMA per quantity per row-tile ----
        f16x4 hf0[4], hf1[4], hf2[4];
#define COMP_H(HF, MT)                                                        \
        {                                                                     \
            f32x4 z = {0, 0, 0, 0};                                           \
            int rrow = ln + 16 * (MT) + 32 * it; if (rrow > 73) rrow = 73;    \
            const _Float16* pr = sr + rrow * SSTR + 16 * nt + 8 * g;          \
            const _Float16* pd = sd + rrow * SSTR + 16 * nt + 8 * g;          \
            union { f16x4 q[2]; f16x8 o; } ur, ud;                            \
            ur.q[0] = *(const f16x4*)(pr);                                    \
            ur.q[1] = *(const f16x4*)(pr + 4);                                \
            ud.q[0] = *(const f16x4*)(pd);                                    \
            ud.q[1] = *(const f16x4*)(pd + 4);                                \
            f16x8 rA = ur.o, dA = ud.o;                                       \
            f16x8 sA = rA + dA, qA = rA - dA;                                 \
            f16x8 ss = sA * sA, qq = qA * qA;                                 \
            f32x4 a0 = __builtin_amdgcn_mfma_f32_16x16x32_f16(rA, wh, z, 0, 0, 0); \
            f32x4 a1 = __builtin_amdgcn_mfma_f32_16x16x32_f16(dA, wh, z, 0, 0, 0); \
            f32x4 a2 = __builtin_amdgcn_mfma_f32_16x16x32_f16(ss, wh, z, 0, 0, 0); \
            f32x4 a3 = __builtin_amdgcn_mfma_f32_16x16x32_f16(qq, wh, z, 0, 0, 0); \
            HF[0] = cvt4(a0); HF[1] = cvt4(a1); HF[2] = cvt4(a2); HF[3] = cvt4(a3); \
        }
        COMP_H(hf0, 0)
        COMP_H(hf1, 1)
        COMP_H(hf2, 2)
#undef COMP_H

        // ---- vertical conv (2x 16x16x16, register B-frags) + f32x2 epilogue ----
#define COMP_O(HA, HB, MTV)                                                   \
        {                                                                     \
            f32x4 z = {0, 0, 0, 0};                                           \
            f32x4 v0 = __builtin_amdgcn_mfma_f32_16x16x16f16(wf0, HA[0], z, 0, 0, 0); \
            f32x4 v1 = __builtin_amdgcn_mfma_f32_16x16x16f16(wf0, HA[1], z, 0, 0, 0); \
            f32x4 v2 = __builtin_amdgcn_mfma_f32_16x16x16f16(wf0, HA[2], z, 0, 0, 0); \
            f32x4 v3 = __builtin_amdgcn_mfma_f32_16x16x16f16(wf0, HA[3], z, 0, 0, 0); \
            v0 = __builtin_amdgcn_mfma_f32_16x16x16f16(wf1, HB[0], v0, 0, 0, 0); \
            v1 = __builtin_amdgcn_mfma_f32_16x16x16f16(wf1, HB[1], v1, 0, 0, 0); \
            v2 = __builtin_amdgcn_mfma_f32_16x16x16f16(wf1, HB[2], v2, 0, 0, 0); \
            v3 = __builtin_amdgcn_mfma_f32_16x16x16f16(wf1, HB[3], v3, 0, 0, 0); \
            int oy0 = ybase32 + 32 * it + 16 * (MTV) + 4 * g;                 \
            if (ox < 502) {                                                   \
                _Pragma("unroll")                                             \
                for (int p = 0; p < 2; ++p) {                                 \
                    f32x2 m1 = {v0[2*p], v0[2*p+1]};                          \
                    f32x2 m2 = {v1[2*p], v1[2*p+1]};                          \
                    f32x2 A  = {v2[2*p], v2[2*p+1]};                          \
                    f32x2 B  = {v3[2*p], v3[2*p+1]};                          \
                    f32x2 m1s = m1 * m1, m2s = m2 * m2, m12 = m1 * m2;        \
                    f32x2 P = m1s + m2s;                                      \
                    f32x2 num1 = 2.f * m12 + 6.5025f;                         \
                    f32x2 num2 = 0.5f * (A - B) - 2.f * m12 + 58.5225f;       \
                    f32x2 den1 = P + 6.5025f;                                 \
                    f32x2 den2 = 0.5f * (A + B) - P + 58.5225f;               \
                    f32x2 num = num1 * num2, den = den1 * den2;               \
                    if (oy0 + 2*p     < 502) lsum += __fdividef(num[0], den[0]); \
                    if (oy0 + 2*p + 1 < 502) lsum += __fdividef(num[1], den[1]); \
                }                                                             \
            }                                                                 \
        }
        COMP_O(hf0, hf1, 0)
        COMP_O(hf1, hf2, 1)
#undef COMP_O
    }

    // ---- wave reduce -> PLAIN STORE to unique slot (no atomics, no memset) ----
#pragma unroll
    for (int off = 32; off; off >>= 1) lsum += __shfl_down(lsum, off);
    if (lane == 0) buckets[wg * 4 + wv] = lsum;
}

// finalize: sum nwg*4 slots (as nwg float4s), 256 threads
__global__ __launch_bounds__(256) void ssim_finalize(
    const float* __restrict__ buckets, float* __restrict__ out,
    float inv, int n4)
{
    __shared__ float sred[4];
    int tid = threadIdx.x;
    float s = 0.f;
    const float4* b4 = (const float4*)buckets;
    for (int i = tid; i < n4; i += 256) {
        float4 v = b4[i];
        s += (v.x + v.y) + (v.z + v.w);
    }
#pragma unroll
    for (int off = 32; off; off >>= 1) s += __shfl_down(s, off);
    if ((tid & 63) == 0) sred[tid >> 6] = s;
    __syncthreads();
    if (tid == 0) out[0] = ((sred[0] + sred[1]) + (sred[2] + sred[3])) * inv;
}

extern "C" void kernel_launch(void* const* d_in, const int* in_sizes, int n_in,
                              void* d_out, int out_size, void* d_ws, size_t ws_size,
                              hipStream_t stream) {
    const float* raw = (const float*)d_in[0];
    const float* dst = (const float*)d_in[1];
    const float* win = (const float*)d_in[2];
    float* out = (float*)d_out;
    float* ws = (float*)d_ws;

    int nimg = in_sizes[0] / (512 * 512);      // B*C = 48
    float inv = 1.0f / ((float)nimg * 502.f * 502.f);
    int nwg = 64 * nimg;                       // 8x8 regions per image

    ssim_main<<<nwg, 256, 0, stream>>>(raw, dst, win, ws);
    ssim_finalize<<<1, 256, 0, stream>>>(ws, out, inv, nwg);
}

// Round 23
// 29.107 us; speedup vs baseline: 1.0697x; 1.0697x over previous
//
#include <hip/hip_runtime.h>

typedef _Float16 f16x4 __attribute__((ext_vector_type(4)));
typedef _Float16 f16x8 __attribute__((ext_vector_type(8)));
typedef __fp16 fp16x2 __attribute__((ext_vector_type(2)));   // cvt_pkrtz return type
typedef float f32x4 __attribute__((ext_vector_type(4)));
typedef float f32x2 __attribute__((ext_vector_type(2)));

#define SSTR 88              // row stride in halves (16B-aligned rows for b128; best: R21)
#define NROWS 74             // staged rows (64 outputs + 10 halo)
#define NPT 6                // staging pair-tasks per thread (1480/256 = 5.8)

__device__ __forceinline__ f16x4 cvt4(f32x4 a)
{
    union { fp16x2 h2[2]; f16x4 f; } u;
    u.h2[0] = __builtin_amdgcn_cvt_pkrtz(a[0], a[1]);
    u.h2[1] = __builtin_amdgcn_cvt_pkrtz(a[2], a[3]);
    return u.f;
}

// ---- main: 64x64 output region per block (2 x 64x32 tiles), 4 waves, ONE barrier.
// H-pass: one mfma_f32_16x16x32_f16 per quantity; D-frag (row=4g+j) feeds vertical
// 16x16x16 B-frags directly in registers (validated R3/R5-R22).
// Quantities: mu1, mu2, A=conv((r+d)^2), B=conv((r-d)^2).
// XCD-bijective swizzle (R17: FETCH 71->49MB). Paired-chunk staging + b128 LDS (R19/R21).
// Plain-store buckets, no memset (R20). LDS weight table (R21). Incremental decode (R22).
__global__ __launch_bounds__(256, 4) void ssim_main(
    const float* __restrict__ raw, const float* __restrict__ dst,
    const float* __restrict__ win, float* __restrict__ buckets)
{
    __shared__ __align__(16) _Float16 sr[NROWS * SSTR];
    __shared__ __align__(16) _Float16 sd[NROWS * SSTR];
    __shared__ __align__(16) _Float16 wrot[4][64];   // wrot[r][i] = w1[i+r-16] (0 outside)

    const int tid = threadIdx.x;
    const int wv = tid >> 6;           // wave = 16-wide x-strip
    const int lane = tid & 63;
    const int g = lane >> 4;
    const int ln = lane & 15;
    const int nt = wv;

    // XCD-bijective swizzle: 3072 blocks = 8 XCDs x 384-contiguous runs (R17)
    const int wg = blockIdx.x;
    const int sw = (wg & 7) * 384 + (wg >> 3);
    const int bz = sw >> 6;
    const int bx = sw & 7;
    const int by = (sw >> 3) & 7;

    const int gx0 = bx * 64;
    const int ybase32 = by * 64;                // first input row of the region
    const long ioff = (long)bz * (512 * 512);
    const float* rb = raw + ioff;
    const float* db = dst + ioff;

    // ---- staging: 1480 pair-tasks = 74 rows x {r,d} x 10 chunk-pairs (R19).
    // Incremental decode (R22): pc += 6 (mod 10), sub += 25 (+carry) per k.
    float4 fvA[NPT], fvB[NPT];
    _Float16* dsts[NPT];
    const bool fastpath = (gx0 < 448) && (ybase32 < 448);
    {
        int pc = tid % 10;
        int sub = tid / 10;
        if (fastpath) {
#pragma unroll
            for (int k = 0; k < NPT; ++k) {
                if (k < NPT - 1 || tid < 200) {
                    int row = sub >> 1;
                    const float* src = ((sub & 1) ? db : rb) + (long)(ybase32 + row) * 512 + gx0 + 8 * pc;
                    fvA[k] = *reinterpret_cast<const float4*>(src);
                    fvB[k] = *reinterpret_cast<const float4*>(src + 4);
                    dsts[k] = ((sub & 1) ? sd : sr) + row * SSTR + pc * 8;
                } else {
                    dsts[k] = nullptr;
                }
                pc += 6; sub += 25;
                if (pc >= 10) { pc -= 10; sub += 1; }
            }
        } else {
#pragma unroll
            for (int k = 0; k < NPT; ++k) {
                if (k < NPT - 1 || tid < 200) {
                    int row = sub >> 1;
                    int gy = ybase32 + row; if (gy > 511) gy = 511;
                    int ca = gx0 + 8 * pc;     if (ca > 508) ca = 508;
                    int cb = ca + 4;           if (cb > 508) cb = 508;
                    const float* rowp = ((sub & 1) ? db : rb) + (long)gy * 512;
                    fvA[k] = *reinterpret_cast<const float4*>(rowp + ca);
                    fvB[k] = *reinterpret_cast<const float4*>(rowp + cb);
                    dsts[k] = ((sub & 1) ? sd : sr) + row * SSTR + pc * 8;
                } else {
                    dsts[k] = nullptr;
                }
                pc += 6; sub += 25;
                if (pc >= 10) { pc -= 10; sub += 1; }
            }
        }
    }

    // ---- rotated padded weight copies (pre-barrier; hides under staging loads) ----
    {
        int r = tid >> 6, i = tid & 63;
        int idx = i + r - 16;
        float val = 0.f;
        if (idx >= 0 && idx <= 10) {
#pragma unroll
            for (int j = 0; j < 11; ++j) val += win[idx * 11 + j];
        }
        wrot[r][i] = (_Float16)val;
    }

#pragma unroll
    for (int k = 0; k < NPT; ++k) {
        if (dsts[k]) {
            union { fp16x2 h2[4]; uint4 u; } pk;
            pk.h2[0] = __builtin_amdgcn_cvt_pkrtz(fvA[k].x, fvA[k].y);
            pk.h2[1] = __builtin_amdgcn_cvt_pkrtz(fvA[k].z, fvA[k].w);
            pk.h2[2] = __builtin_amdgcn_cvt_pkrtz(fvB[k].x, fvB[k].y);
            pk.h2[3] = __builtin_amdgcn_cvt_pkrtz(fvB[k].z, fvB[k].w);
            *reinterpret_cast<uint4*>(dsts[k]) = pk.u;     // ds_write_b128
        }
    }
    __syncthreads();

    // ---- weight fragments via aligned LDS reads (R21) ----
    f16x4 wf0, wf1;
    f16x8 wh;
    {
        int s = 4 * g - ln + 16;               // 1..28
        const char* b0 = (const char*)wrot[s & 3] + (s >> 2) * 8;
        wf0 = *(const f16x4*)(b0);
        wf1 = *(const f16x4*)(b0 + 32);        // +16 halves, same rotation
        int s2 = 8 * g - ln + 16;              // 1..40
        const char* b2 = (const char*)wrot[s2 & 3] + (s2 >> 2) * 8;
        union { f16x4 q[2]; f16x8 o; } uu;
        uu.q[0] = *(const f16x4*)(b2);
        uu.q[1] = *(const f16x4*)(b2 + 8);
        wh = uu.o;
    }

    float lsum = 0.f;
    const int ox = gx0 + 16 * nt + ln;

#pragma unroll
    for (int it = 0; it < 2; ++it) {
        // ---- horizontal conv: ONE 16x16x32 MFMA per quantity per row-tile ----
        f16x4 hf0[4], hf1[4], hf2[4];
#define COMP_H(HF, MT)                                                        \
        {                                                                     \
            f32x4 z = {0, 0, 0, 0};                                           \
            int rrow = ln + 16 * (MT) + 32 * it; if (rrow > 73) rrow = 73;    \
            const f16x8 rA = *(const f16x8*)(sr + rrow * SSTR + 16 * nt + 8 * g); \
            const f16x8 dA = *(const f16x8*)(sd + rrow * SSTR + 16 * nt + 8 * g); \
            f16x8 sA = rA + dA, qA = rA - dA;                                 \
            f16x8 ss = sA * sA, qq = qA * qA;                                 \
            f32x4 a0 = __builtin_amdgcn_mfma_f32_16x16x32_f16(rA, wh, z, 0, 0, 0); \
            f32x4 a1 = __builtin_amdgcn_mfma_f32_16x16x32_f16(dA, wh, z, 0, 0, 0); \
            f32x4 a2 = __builtin_amdgcn_mfma_f32_16x16x32_f16(ss, wh, z, 0, 0, 0); \
            f32x4 a3 = __builtin_amdgcn_mfma_f32_16x16x32_f16(qq, wh, z, 0, 0, 0); \
            HF[0] = cvt4(a0); HF[1] = cvt4(a1); HF[2] = cvt4(a2); HF[3] = cvt4(a3); \
        }
        COMP_H(hf0, 0)
        COMP_H(hf1, 1)
        COMP_H(hf2, 2)
#undef COMP_H

        // ---- vertical conv (2x 16x16x16, register B-frags) + f32x2 epilogue ----
#define COMP_O(HA, HB, MTV)                                                   \
        {                                                                     \
            f32x4 z = {0, 0, 0, 0};                                           \
            f32x4 v0 = __builtin_amdgcn_mfma_f32_16x16x16f16(wf0, HA[0], z, 0, 0, 0); \
            f32x4 v1 = __builtin_amdgcn_mfma_f32_16x16x16f16(wf0, HA[1], z, 0, 0, 0); \
            f32x4 v2 = __builtin_amdgcn_mfma_f32_16x16x16f16(wf0, HA[2], z, 0, 0, 0); \
            f32x4 v3 = __builtin_amdgcn_mfma_f32_16x16x16f16(wf0, HA[3], z, 0, 0, 0); \
            v0 = __builtin_amdgcn_mfma_f32_16x16x16f16(wf1, HB[0], v0, 0, 0, 0); \
            v1 = __builtin_amdgcn_mfma_f32_16x16x16f16(wf1, HB[1], v1, 0, 0, 0); \
            v2 = __builtin_amdgcn_mfma_f32_16x16x16f16(wf1, HB[2], v2, 0, 0, 0); \
            v3 = __builtin_amdgcn_mfma_f32_16x16x16f16(wf1, HB[3], v3, 0, 0, 0); \
            int oy0 = ybase32 + 32 * it + 16 * (MTV) + 4 * g;                 \
            if (ox < 502) {                                                   \
                _Pragma("unroll")                                             \
                for (int p = 0; p < 2; ++p) {                                 \
                    f32x2 m1 = {v0[2*p], v0[2*p+1]};                          \
                    f32x2 m2 = {v1[2*p], v1[2*p+1]};                          \
                    f32x2 A  = {v2[2*p], v2[2*p+1]};                          \
                    f32x2 B  = {v3[2*p], v3[2*p+1]};                          \
                    f32x2 m1s = m1 * m1, m2s = m2 * m2, m12 = m1 * m2;        \
                    f32x2 P = m1s + m2s;                                      \
                    f32x2 num1 = 2.f * m12 + 6.5025f;                         \
                    f32x2 num2 = 0.5f * (A - B) - 2.f * m12 + 58.5225f;       \
                    f32x2 den1 = P + 6.5025f;                                 \
                    f32x2 den2 = 0.5f * (A + B) - P + 58.5225f;               \
                    f32x2 num = num1 * num2, den = den1 * den2;               \
                    if (oy0 + 2*p     < 502) lsum += __fdividef(num[0], den[0]); \
                    if (oy0 + 2*p + 1 < 502) lsum += __fdividef(num[1], den[1]); \
                }                                                             \
            }                                                                 \
        }
        COMP_O(hf0, hf1, 0)
        COMP_O(hf1, hf2, 1)
#undef COMP_O
    }

    // ---- wave reduce -> PLAIN STORE to unique slot (no atomics, no memset) ----
#pragma unroll
    for (int off = 32; off; off >>= 1) lsum += __shfl_down(lsum, off);
    if (lane == 0) buckets[wg * 4 + wv] = lsum;
}

// finalize: sum nwg*4 slots (as nwg float4s), 1024 threads (3 loads/thread)
__global__ __launch_bounds__(1024) void ssim_finalize(
    const float* __restrict__ buckets, float* __restrict__ out,
    float inv, int n4)
{
    __shared__ float sred[16];
    int tid = threadIdx.x;
    float s = 0.f;
    const float4* b4 = (const float4*)buckets;
    for (int i = tid; i < n4; i += 1024) {
        float4 v = b4[i];
        s += (v.x + v.y) + (v.z + v.w);
    }
#pragma unroll
    for (int off = 32; off; off >>= 1) s += __shfl_down(s, off);
    if ((tid & 63) == 0) sred[tid >> 6] = s;
    __syncthreads();
    if (tid < 64) {
        float t = (tid < 16) ? sred[tid] : 0.f;
#pragma unroll
        for (int off = 8; off; off >>= 1) t += __shfl_down(t, off);
        if (tid == 0) out[0] = t * inv;
    }
}

extern "C" void kernel_launch(void* const* d_in, const int* in_sizes, int n_in,
                              void* d_out, int out_size, void* d_ws, size_t ws_size,
                              hipStream_t stream) {
    const float* raw = (const float*)d_in[0];
    const float* dst = (const float*)d_in[1];
    const float* win = (const float*)d_in[2];
    float* out = (float*)d_out;
    float* ws = (float*)d_ws;

    int nimg = in_sizes[0] / (512 * 512);      // B*C = 48
    float inv = 1.0f / ((float)nimg * 502.f * 502.f);
    int nwg = 64 * nimg;                       // 8x8 regions per image

    ssim_main<<<nwg, 256, 0, stream>>>(raw, dst, win, ws);
    ssim_finalize<<<1, 1024, 0, stream>>>(ws, out, inv, nwg);
}